// Round 3
// baseline (461.471 us; speedup 1.0000x reference)
//
#include <hip/hip_runtime.h>

#define NN 50000
#define NE 800000
#define DIN 96
#define DH 128
#define DOUT 16

// ---------------- CSR build: histogram, scan, fill ----------------
__global__ __launch_bounds__(256) void k_hist(const int* __restrict__ ei, int* __restrict__ cnt) {
    int e = blockIdx.x * 256 + threadIdx.x;
    if (e < NE) atomicAdd(&cnt[ei[NE + e]], 1);
}

__global__ __launch_bounds__(1024) void k_scan(const int* __restrict__ cnt, int* __restrict__ off) {
    __shared__ int buf[1024];
    const int per = (NN + 1023) / 1024;   // 49
    const int tid = threadIdx.x;
    const int b = tid * per;
    const int e = min(b + per, NN);
    int s = 0;
    for (int i = b; i < e; ++i) s += cnt[i];
    buf[tid] = s;
    __syncthreads();
    for (int o = 1; o < 1024; o <<= 1) {
        int t = (tid >= o) ? buf[tid - o] : 0;
        __syncthreads();
        buf[tid] += t;
        __syncthreads();
    }
    int run = buf[tid] - s;               // exclusive prefix of this thread's chunk
    for (int i = b; i < e; ++i) { off[i] = run; run += cnt[i]; }
    if (tid == 1023) off[NN] = NE;
}

__global__ __launch_bounds__(256) void k_fill(const int* __restrict__ ei, const int* __restrict__ off,
                                              int* __restrict__ cur, int* __restrict__ csr) {
    int e = blockIdx.x * 256 + threadIdx.x;
    if (e < NE) {
        int d = ei[NE + e];
        int p = atomicAdd(&cur[d], 1);
        csr[off[d] + p] = ei[e];
    }
}

// ---------------- gather mean-aggregate (one wave per node, float2 lanes) ----------------
template <int D2>   // number of float2 per row: DIN->48, DH->64
__global__ __launch_bounds__(256) void k_agg(const float* __restrict__ feat,
                                             const int* __restrict__ csr,
                                             const int* __restrict__ off,
                                             float* __restrict__ mean) {
    const int w = threadIdx.x >> 6;     // 4 waves per block, one node each
    const int l = threadIdx.x & 63;
    const int n = blockIdx.x * 4 + w;
    if (n >= NN || l >= D2) return;
    const int b = off[n], e = off[n + 1];
    const float2* f2 = (const float2*)feat;
    float2 acc = {0.f, 0.f};
    int i = b;
    for (; i + 1 < e; i += 2) {
        int s0 = csr[i], s1 = csr[i + 1];
        float2 v0 = f2[(size_t)s0 * D2 + l];
        float2 v1 = f2[(size_t)s1 * D2 + l];
        acc.x += v0.x + v1.x;
        acc.y += v0.y + v1.y;
    }
    if (i < e) {
        float2 v = f2[(size_t)csr[i] * D2 + l];
        acc.x += v.x; acc.y += v.y;
    }
    const float inv = (e > b) ? 1.0f / (float)(e - b) : 0.0f;
    acc.x *= inv; acc.y *= inv;
    ((float2*)mean)[(size_t)n * D2 + l] = acc;
}

// ---------------- layer 1 dense: h = relu(mean1 @ W1l + b1 + x @ W1r), 16 nodes/block ----------------
__global__ __launch_bounds__(128) void k_lin1(const float* __restrict__ x,
                                              const float* __restrict__ mean1,
                                              const float* __restrict__ W1l,
                                              const float* __restrict__ b1,
                                              const float* __restrict__ W1r,
                                              float* __restrict__ h) {
    __shared__ float4 sx[16][DIN / 4];
    __shared__ float4 sa[16][DIN / 4];
    const int nb = blockIdx.x * 16;
    const int tid = threadIdx.x;
    const float4* x4 = (const float4*)(x + (size_t)nb * DIN);
    const float4* a4 = (const float4*)(mean1 + (size_t)nb * DIN);
#pragma unroll
    for (int it = 0; it < 3; ++it) {
        int idx = tid + it * 128;               // 0..383
        int m = idx / (DIN / 4), q = idx % (DIN / 4);
        sx[m][q] = x4[idx];
        sa[m][q] = a4[idx];
    }
    __syncthreads();
    float acc[16];
    const float bj = b1[tid];
#pragma unroll
    for (int m = 0; m < 16; ++m) acc[m] = bj;
    const float* sxf = (const float*)sx;
    const float* saf = (const float*)sa;
    const float* pl = W1l + tid;
    const float* pr = W1r + tid;
    for (int k = 0; k < DIN; ++k) {
        const float wl = pl[k * DH];
        const float wr = pr[k * DH];
#pragma unroll
        for (int m = 0; m < 16; ++m)
            acc[m] += saf[m * DIN + k] * wl + sxf[m * DIN + k] * wr;
    }
#pragma unroll
    for (int m = 0; m < 16; ++m)
        h[(size_t)(nb + m) * DH + tid] = fmaxf(acc[m], 0.0f);
}

// ---------------- layer 2 dense + softmax ----------------
__global__ __launch_bounds__(256) void k_lin2(const float* __restrict__ h,
                                              const float* __restrict__ mean2,
                                              const float* __restrict__ W2l,
                                              const float* __restrict__ b2,
                                              const float* __restrict__ W2r,
                                              float* __restrict__ out) {
    __shared__ float sh[4][2 * DH];
    const int wid  = threadIdx.x >> 6;
    const int lane = threadIdx.x & 63;
    const int n = blockIdx.x * 4 + wid;
    if (lane < 32) {
        float4 v = ((const float4*)(h + (size_t)n * DH))[lane];
        ((float4*)&sh[wid][0])[lane] = v;
    } else {
        float4 v = ((const float4*)(mean2 + (size_t)n * DH))[lane - 32];
        ((float4*)&sh[wid][DH])[lane - 32] = v;
    }
    __syncthreads();
    const int oc = lane >> 2;
    const int kq = lane & 3;
    float acc = 0.0f;
#pragma unroll 4
    for (int i = 0; i < 32; ++i) {
        const int k = kq * 32 + i;
        acc += sh[wid][k] * W2r[k * DOUT + oc];
        acc += sh[wid][DH + k] * W2l[k * DOUT + oc];
    }
    acc += __shfl_xor(acc, 1);
    acc += __shfl_xor(acc, 2);
    acc += b2[oc];
    float mx = acc;
#pragma unroll
    for (int off = 4; off <= 32; off <<= 1) mx = fmaxf(mx, __shfl_xor(mx, off));
    const float ev = expf(acc - mx);
    float ssum = ev;
#pragma unroll
    for (int off = 4; off <= 32; off <<= 1) ssum += __shfl_xor(ssum, off);
    if (kq == 0) out[(size_t)n * DOUT + oc] = ev / ssum;
}

extern "C" void kernel_launch(void* const* d_in, const int* in_sizes, int n_in,
                              void* d_out, int out_size, void* d_ws, size_t ws_size,
                              hipStream_t stream) {
    const float* x   = (const float*)d_in[0];
    const int*   ei  = (const int*)d_in[1];
    const float* W1l = (const float*)d_in[2];
    const float* b1  = (const float*)d_in[3];
    const float* W1r = (const float*)d_in[4];
    const float* W2l = (const float*)d_in[5];
    const float* b2  = (const float*)d_in[6];
    const float* W2r = (const float*)d_in[7];
    float* out = (float*)d_out;

    // workspace layout (ints first, then floats)
    int* cnt = (int*)d_ws;                       // NN
    int* cur = cnt + NN;                         // NN
    int* off = cur + NN;                         // NN + 1
    int* csr = off + NN + 1;                     // NE
    float* mean1 = (float*)(csr + NE);           // NN*DIN
    float* h     = mean1 + (size_t)NN * DIN;     // NN*DH
    float* mean2 = h + (size_t)NN * DH;          // NN*DH

    hipMemsetAsync(cnt, 0, (size_t)2 * NN * sizeof(int), stream);  // cnt + cur

    const int eblocks = (NE + 255) / 256;
    k_hist<<<eblocks, 256, 0, stream>>>(ei, cnt);
    k_scan<<<1, 1024, 0, stream>>>(cnt, off);
    k_fill<<<eblocks, 256, 0, stream>>>(ei, off, cur, csr);

    k_agg<DIN / 2><<<(NN + 3) / 4, 256, 0, stream>>>(x, csr, off, mean1);
    k_lin1<<<NN / 16, 128, 0, stream>>>(x, mean1, W1l, b1, W1r, h);
    k_agg<DH / 2><<<(NN + 3) / 4, 256, 0, stream>>>(h, csr, off, mean2);
    k_lin2<<<NN / 4, 256, 0, stream>>>(h, mean2, W2l, b2, W2r, out);
}

// Round 4
// 330.880 us; speedup vs baseline: 1.3947x; 1.3947x over previous
//
#include <hip/hip_runtime.h>

#define NN 50000
#define NE 800000
#define DIN 96
#define DH 128
#define DOUT 16

// ---------------- CSR build: histogram, scan, fill ----------------
__global__ __launch_bounds__(256) void k_hist(const int* __restrict__ ei, int* __restrict__ cnt) {
    int e = blockIdx.x * 256 + threadIdx.x;
    if (e < NE) atomicAdd(&cnt[ei[NE + e]], 1);
}

__global__ __launch_bounds__(1024) void k_scan(const int* __restrict__ cnt, int* __restrict__ off) {
    __shared__ int buf[1024];
    const int per = (NN + 1023) / 1024;   // 49
    const int tid = threadIdx.x;
    const int b = tid * per;
    const int e = min(b + per, NN);
    int s = 0;
    for (int i = b; i < e; ++i) s += cnt[i];
    buf[tid] = s;
    __syncthreads();
    for (int o = 1; o < 1024; o <<= 1) {
        int t = (tid >= o) ? buf[tid - o] : 0;
        __syncthreads();
        buf[tid] += t;
        __syncthreads();
    }
    int run = buf[tid] - s;
    for (int i = b; i < e; ++i) { off[i] = run; run += cnt[i]; }
    if (tid == 1023) off[NN] = NE;
}

__global__ __launch_bounds__(256) void k_fill(const int* __restrict__ ei, const int* __restrict__ off,
                                              int* __restrict__ cur, int* __restrict__ csr) {
    int e = blockIdx.x * 256 + threadIdx.x;
    if (e < NE) {
        int d = ei[NE + e];
        int p = atomicAdd(&cur[d], 1);
        csr[off[d] + p] = ei[e];
    }
}

// ---------------- agg1: mean over neighbors of x (96-dim), one wave per node ----------------
__global__ __launch_bounds__(256) void k_agg1(const float* __restrict__ x,
                                              const int* __restrict__ csr,
                                              const int* __restrict__ off,
                                              float* __restrict__ mean1) {
    const int w = threadIdx.x >> 6;
    const int l = threadIdx.x & 63;
    const int n = blockIdx.x * 4 + w;
    if (n >= NN || l >= DIN / 2) return;
    const int b = off[n], e = off[n + 1];
    const float2* f2 = (const float2*)x;
    float2 acc = {0.f, 0.f};
    int i = b;
    for (; i + 3 < e; i += 4) {
        int s0 = csr[i], s1 = csr[i + 1], s2 = csr[i + 2], s3 = csr[i + 3];
        float2 v0 = f2[(size_t)s0 * (DIN / 2) + l];
        float2 v1 = f2[(size_t)s1 * (DIN / 2) + l];
        float2 v2 = f2[(size_t)s2 * (DIN / 2) + l];
        float2 v3 = f2[(size_t)s3 * (DIN / 2) + l];
        acc.x += (v0.x + v1.x) + (v2.x + v3.x);
        acc.y += (v0.y + v1.y) + (v2.y + v3.y);
    }
    for (; i < e; ++i) {
        float2 v = f2[(size_t)csr[i] * (DIN / 2) + l];
        acc.x += v.x; acc.y += v.y;
    }
    const float inv = (e > b) ? 1.0f / (float)(e - b) : 0.0f;
    acc.x *= inv; acc.y *= inv;
    ((float2*)mean1)[(size_t)n * (DIN / 2) + l] = acc;
}

// ---------------- lin1: h = relu(mean1 @ W1l + b1 + x @ W1r), 64-node tile GEMM ----------------
#define BM1 64
__global__ __launch_bounds__(256) void k_lin1(const float* __restrict__ x,
                                              const float* __restrict__ mean1,
                                              const float* __restrict__ W1l,
                                              const float* __restrict__ b1,
                                              const float* __restrict__ W1r,
                                              float* __restrict__ h) {
    __shared__ float sx[BM1][DIN];
    __shared__ float sa[BM1][DIN];
    const int nb = blockIdx.x * BM1;
    const int tid = threadIdx.x;
    const float4* x4 = (const float4*)x;
    const float4* a4 = (const float4*)mean1;
    float4* sx4 = (float4*)sx;
    float4* sa4 = (float4*)sa;
#pragma unroll
    for (int it = 0; it < 6; ++it) {
        int idx = tid + it * 256;                 // 0..1535
        int m = idx / (DIN / 4), q = idx % (DIN / 4);
        int row = nb + m; row = row < NN ? row : NN - 1;
        sx4[idx] = x4[(size_t)row * (DIN / 4) + q];
        sa4[idx] = a4[(size_t)row * (DIN / 4) + q];
    }
    __syncthreads();
    const int n0 = (tid & 31) * 4;
    const int m0 = (tid >> 5) * 8;
    float4 acc[8];
    const float4 bv = *(const float4*)&b1[n0];
#pragma unroll
    for (int i = 0; i < 8; ++i) acc[i] = bv;
    for (int k = 0; k < DIN; k += 4) {
        const float4 wl0 = *(const float4*)&W1l[(k + 0) * DH + n0];
        const float4 wl1 = *(const float4*)&W1l[(k + 1) * DH + n0];
        const float4 wl2 = *(const float4*)&W1l[(k + 2) * DH + n0];
        const float4 wl3 = *(const float4*)&W1l[(k + 3) * DH + n0];
        const float4 wr0 = *(const float4*)&W1r[(k + 0) * DH + n0];
        const float4 wr1 = *(const float4*)&W1r[(k + 1) * DH + n0];
        const float4 wr2 = *(const float4*)&W1r[(k + 2) * DH + n0];
        const float4 wr3 = *(const float4*)&W1r[(k + 3) * DH + n0];
#pragma unroll
        for (int i = 0; i < 8; ++i) {
            const float4 av = *(const float4*)&sa[m0 + i][k];
            const float4 xv = *(const float4*)&sx[m0 + i][k];
            acc[i].x += av.x * wl0.x + av.y * wl1.x + av.z * wl2.x + av.w * wl3.x
                      + xv.x * wr0.x + xv.y * wr1.x + xv.z * wr2.x + xv.w * wr3.x;
            acc[i].y += av.x * wl0.y + av.y * wl1.y + av.z * wl2.y + av.w * wl3.y
                      + xv.x * wr0.y + xv.y * wr1.y + xv.z * wr2.y + xv.w * wr3.y;
            acc[i].z += av.x * wl0.z + av.y * wl1.z + av.z * wl2.z + av.w * wl3.z
                      + xv.x * wr0.z + xv.y * wr1.z + xv.z * wr2.z + xv.w * wr3.z;
            acc[i].w += av.x * wl0.w + av.y * wl1.w + av.z * wl2.w + av.w * wl3.w
                      + xv.x * wr0.w + xv.y * wr1.w + xv.z * wr2.w + xv.w * wr3.w;
        }
    }
#pragma unroll
    for (int i = 0; i < 8; ++i) {
        int row = nb + m0 + i;
        if (row < NN) {
            float4 v = acc[i];
            v.x = fmaxf(v.x, 0.f); v.y = fmaxf(v.y, 0.f);
            v.z = fmaxf(v.z, 0.f); v.w = fmaxf(v.w, 0.f);
            *(float4*)&h[(size_t)row * DH + n0] = v;
        }
    }
}

// ---------------- proj: zl = h @ W2l ; s = h @ W2r + b2 (per-node, pre-aggregation) ----------------
#define BM2 64
__global__ __launch_bounds__(256) void k_proj(const float* __restrict__ h,
                                              const float* __restrict__ W2l,
                                              const float* __restrict__ b2,
                                              const float* __restrict__ W2r,
                                              float* __restrict__ zl,
                                              float* __restrict__ s) {
    __shared__ float sh[BM2][DH + 4];
    const int nb = blockIdx.x * BM2;
    const int tid = threadIdx.x;
#pragma unroll
    for (int it = 0; it < 8; ++it) {
        int idx = tid + it * 256;                 // 0..2047
        int m = idx >> 5, q = idx & 31;
        int row = nb + m; row = row < NN ? row : NN - 1;
        *(float4*)&sh[m][q * 4] = ((const float4*)h)[(size_t)row * (DH / 4) + q];
    }
    __syncthreads();
    const int n0 = (tid & 3) * 4;
    const int tm = tid >> 2;                      // one node per thread
    float4 al = {0.f, 0.f, 0.f, 0.f};
    float4 ar = *(const float4*)&b2[n0];
    for (int k = 0; k < DH; k += 4) {
        const float4 wl0 = *(const float4*)&W2l[(k + 0) * DOUT + n0];
        const float4 wl1 = *(const float4*)&W2l[(k + 1) * DOUT + n0];
        const float4 wl2 = *(const float4*)&W2l[(k + 2) * DOUT + n0];
        const float4 wl3 = *(const float4*)&W2l[(k + 3) * DOUT + n0];
        const float4 wr0 = *(const float4*)&W2r[(k + 0) * DOUT + n0];
        const float4 wr1 = *(const float4*)&W2r[(k + 1) * DOUT + n0];
        const float4 wr2 = *(const float4*)&W2r[(k + 2) * DOUT + n0];
        const float4 wr3 = *(const float4*)&W2r[(k + 3) * DOUT + n0];
        const float4 hv = *(const float4*)&sh[tm][k];
        al.x += hv.x * wl0.x + hv.y * wl1.x + hv.z * wl2.x + hv.w * wl3.x;
        al.y += hv.x * wl0.y + hv.y * wl1.y + hv.z * wl2.y + hv.w * wl3.y;
        al.z += hv.x * wl0.z + hv.y * wl1.z + hv.z * wl2.z + hv.w * wl3.z;
        al.w += hv.x * wl0.w + hv.y * wl1.w + hv.z * wl2.w + hv.w * wl3.w;
        ar.x += hv.x * wr0.x + hv.y * wr1.x + hv.z * wr2.x + hv.w * wr3.x;
        ar.y += hv.x * wr0.y + hv.y * wr1.y + hv.z * wr2.y + hv.w * wr3.y;
        ar.z += hv.x * wr0.z + hv.y * wr1.z + hv.z * wr2.z + hv.w * wr3.z;
        ar.w += hv.x * wr0.w + hv.y * wr1.w + hv.z * wr2.w + hv.w * wr3.w;
    }
    const int row = nb + tm;
    if (row < NN) {
        *(float4*)&zl[(size_t)row * DOUT + n0] = al;
        *(float4*)&s[(size_t)row * DOUT + n0] = ar;
    }
}

// ---------------- agg2 + softmax: out = softmax(mean(zl_nbr) + s) ----------------
__global__ __launch_bounds__(256) void k_agg2(const float* __restrict__ zl,
                                              const float* __restrict__ s,
                                              const int* __restrict__ csr,
                                              const int* __restrict__ off,
                                              float* __restrict__ out) {
    const int lane = threadIdx.x & 63;
    const int wv = threadIdx.x >> 6;
    const int g = lane >> 2;          // 16 nodes per wave
    const int l4 = lane & 3;          // float4 slot within the 16-float row
    const int n = (blockIdx.x * 4 + wv) * 16 + g;
    if (n >= NN) return;
    const int b = off[n], e = off[n + 1];
    const float4* z4 = (const float4*)zl;
    float4 acc = {0.f, 0.f, 0.f, 0.f};
    int i = b;
    for (; i + 1 < e; i += 2) {
        int s0 = csr[i], s1 = csr[i + 1];
        float4 v0 = z4[(size_t)s0 * 4 + l4];
        float4 v1 = z4[(size_t)s1 * 4 + l4];
        acc.x += v0.x + v1.x; acc.y += v0.y + v1.y;
        acc.z += v0.z + v1.z; acc.w += v0.w + v1.w;
    }
    if (i < e) {
        float4 v = z4[(size_t)csr[i] * 4 + l4];
        acc.x += v.x; acc.y += v.y; acc.z += v.z; acc.w += v.w;
    }
    const float inv = (e > b) ? 1.0f / (float)(e - b) : 0.0f;
    const float4 sv = ((const float4*)s)[(size_t)n * 4 + l4];
    float4 v;
    v.x = acc.x * inv + sv.x;
    v.y = acc.y * inv + sv.y;
    v.z = acc.z * inv + sv.z;
    v.w = acc.w * inv + sv.w;
    // softmax over 16 = 4 components x 4 lanes of the quad
    float mx = fmaxf(fmaxf(v.x, v.y), fmaxf(v.z, v.w));
    mx = fmaxf(mx, __shfl_xor(mx, 1));
    mx = fmaxf(mx, __shfl_xor(mx, 2));
    v.x = expf(v.x - mx); v.y = expf(v.y - mx);
    v.z = expf(v.z - mx); v.w = expf(v.w - mx);
    float sm = v.x + v.y + v.z + v.w;
    sm += __shfl_xor(sm, 1);
    sm += __shfl_xor(sm, 2);
    const float r = 1.0f / sm;
    v.x *= r; v.y *= r; v.z *= r; v.w *= r;
    ((float4*)out)[(size_t)n * 4 + l4] = v;
}

extern "C" void kernel_launch(void* const* d_in, const int* in_sizes, int n_in,
                              void* d_out, int out_size, void* d_ws, size_t ws_size,
                              hipStream_t stream) {
    const float* x   = (const float*)d_in[0];
    const int*   ei  = (const int*)d_in[1];
    const float* W1l = (const float*)d_in[2];
    const float* b1  = (const float*)d_in[3];
    const float* W1r = (const float*)d_in[4];
    const float* W2l = (const float*)d_in[5];
    const float* b2  = (const float*)d_in[6];
    const float* W2r = (const float*)d_in[7];
    float* out = (float*)d_out;

    // workspace layout (ints first, then floats)
    int* cnt = (int*)d_ws;                       // NN
    int* cur = cnt + NN;                         // NN
    int* off = cur + NN;                         // NN + 1
    int* csr = off + NN + 1;                     // NE
    float* mean1 = (float*)(csr + NE);           // NN*DIN
    float* h     = mean1 + (size_t)NN * DIN;     // NN*DH
    float* zl    = h + (size_t)NN * DH;          // NN*DOUT
    float* s     = zl + (size_t)NN * DOUT;       // NN*DOUT

    hipMemsetAsync(cnt, 0, (size_t)2 * NN * sizeof(int), stream);

    const int eblocks = (NE + 255) / 256;
    k_hist<<<eblocks, 256, 0, stream>>>(ei, cnt);
    k_scan<<<1, 1024, 0, stream>>>(cnt, off);
    k_fill<<<eblocks, 256, 0, stream>>>(ei, off, cur, csr);

    k_agg1<<<(NN + 3) / 4, 256, 0, stream>>>(x, csr, off, mean1);
    k_lin1<<<(NN + BM1 - 1) / BM1, 256, 0, stream>>>(x, mean1, W1l, b1, W1r, h);
    k_proj<<<(NN + BM2 - 1) / BM2, 256, 0, stream>>>(h, W2l, b2, W2r, zl, s);
    k_agg2<<<(NN + 63) / 64, 256, 0, stream>>>(zl, s, csr, off, out);
}

// Round 5
// 276.980 us; speedup vs baseline: 1.6661x; 1.1946x over previous
//
#include <hip/hip_runtime.h>

#define NN 50000
#define NE 800000
#define DIN 96
#define DH 128
#define DOUT 16

typedef __attribute__((ext_vector_type(8))) short bf16x8;
typedef __attribute__((ext_vector_type(4))) float f32x4;

__device__ inline short f2bf(float f) {
    unsigned u = __float_as_uint(f);
    u += 0x7fff + ((u >> 16) & 1);          // round-to-nearest-even
    return (short)(u >> 16);
}

// ---------------- CSR build: histogram, scan, fill ----------------
__global__ __launch_bounds__(256) void k_hist(const int* __restrict__ ei, int* __restrict__ cnt) {
    int e = blockIdx.x * 256 + threadIdx.x;
    if (e < NE) atomicAdd(&cnt[ei[NE + e]], 1);
}

__global__ __launch_bounds__(1024) void k_scan(const int* __restrict__ cnt, int* __restrict__ off) {
    __shared__ int buf[1024];
    const int per = (NN + 1023) / 1024;   // 49
    const int tid = threadIdx.x;
    const int b = tid * per;
    const int e = min(b + per, NN);
    int s = 0;
    for (int i = b; i < e; ++i) s += cnt[i];
    buf[tid] = s;
    __syncthreads();
    for (int o = 1; o < 1024; o <<= 1) {
        int t = (tid >= o) ? buf[tid - o] : 0;
        __syncthreads();
        buf[tid] += t;
        __syncthreads();
    }
    int run = buf[tid] - s;
    for (int i = b; i < e; ++i) { off[i] = run; run += cnt[i]; }
    if (tid == 1023) off[NN] = NE;
}

__global__ __launch_bounds__(256) void k_fill(const int* __restrict__ ei, const int* __restrict__ off,
                                              int* __restrict__ cur, int* __restrict__ csr) {
    int e = blockIdx.x * 256 + threadIdx.x;
    if (e < NE) {
        int d = ei[NE + e];
        int p = atomicAdd(&cur[d], 1);
        csr[off[d] + p] = ei[e];
    }
}

// ---------------- casts ----------------
__global__ __launch_bounds__(256) void k_cast_x(const float* __restrict__ x, short* __restrict__ xb) {
    int i = blockIdx.x * 256 + threadIdx.x;       // one float4 -> 4 bf16
    const int total = NN * DIN / 4;
    if (i >= total) return;
    float4 v = ((const float4*)x)[i];
    short4 o;
    o.x = f2bf(v.x); o.y = f2bf(v.y); o.z = f2bf(v.z); o.w = f2bf(v.w);
    ((short4*)xb)[i] = o;
}

// Bt[n][kk] bf16, kk<96 -> W1l[kk][n], else W1r[kk-96][n]
__global__ __launch_bounds__(256) void k_cast_w(const float* __restrict__ W1l,
                                                const float* __restrict__ W1r,
                                                short* __restrict__ Bt) {
    int idx = blockIdx.x * 256 + threadIdx.x;     // n*192 + kk
    if (idx >= DH * 192) return;
    int n = idx / 192, kk = idx % 192;
    float v = (kk < DIN) ? W1l[kk * DH + n] : W1r[(kk - DIN) * DH + n];
    Bt[idx] = f2bf(v);
}

// ---------------- agg1: mean over neighbors of xb (bf16, 96-dim); one wave/node ----------------
__global__ __launch_bounds__(256) void k_agg1(const short* __restrict__ xb,
                                              const int* __restrict__ csr,
                                              const int* __restrict__ off,
                                              short* __restrict__ m1b) {
    const int w = threadIdx.x >> 6;
    const int l = threadIdx.x & 63;               // lane handles 2 bf16 (one uint)
    const int n = blockIdx.x * 4 + w;
    if (n >= NN || l >= DIN / 2) return;
    const int b = off[n], e = off[n + 1];
    const unsigned* xu = (const unsigned*)xb;     // row = 48 uints
    float ax = 0.f, ay = 0.f;
    int i = b;
    for (; i + 3 < e; i += 4) {
        unsigned u0 = xu[(size_t)csr[i]     * (DIN / 2) + l];
        unsigned u1 = xu[(size_t)csr[i + 1] * (DIN / 2) + l];
        unsigned u2 = xu[(size_t)csr[i + 2] * (DIN / 2) + l];
        unsigned u3 = xu[(size_t)csr[i + 3] * (DIN / 2) + l];
        ax += __uint_as_float(u0 << 16) + __uint_as_float(u1 << 16)
            + __uint_as_float(u2 << 16) + __uint_as_float(u3 << 16);
        ay += __uint_as_float(u0 & 0xffff0000u) + __uint_as_float(u1 & 0xffff0000u)
            + __uint_as_float(u2 & 0xffff0000u) + __uint_as_float(u3 & 0xffff0000u);
    }
    for (; i < e; ++i) {
        unsigned u = xu[(size_t)csr[i] * (DIN / 2) + l];
        ax += __uint_as_float(u << 16);
        ay += __uint_as_float(u & 0xffff0000u);
    }
    const float inv = (e > b) ? 1.0f / (float)(e - b) : 0.0f;
    ax *= inv; ay *= inv;
    unsigned o = (unsigned)(unsigned short)f2bf(ax) | ((unsigned)(unsigned short)f2bf(ay) << 16);
    ((unsigned*)m1b)[(size_t)n * (DIN / 2) + l] = o;
}

// ---------------- lin1 MFMA: h = relu([m1b, xb] @ Bt^T + b1), 64 rows/block ----------------
__global__ __launch_bounds__(256) void k_lin1(const short* __restrict__ m1b,
                                              const short* __restrict__ xb,
                                              const short* __restrict__ Bt,
                                              const float* __restrict__ b1,
                                              float* __restrict__ h) {
    const int w = threadIdx.x >> 6;
    const int l = threadIdx.x & 63;
    const int lr = l & 15;                        // A-row / B-col within tile
    const int lk = l >> 4;                        // k-group (8 bf16 each)
    int row = blockIdx.x * 64 + w * 16 + lr;
    if (row >= NN) row = NN - 1;                  // clamp loads; stores guarded

    f32x4 acc[8];
#pragma unroll
    for (int nt = 0; nt < 8; ++nt) {
        float bv = b1[nt * 16 + lr];
        acc[nt] = (f32x4){bv, bv, bv, bv};
    }

    bf16x8 afr[6];
    {
        const bf16x8* am = (const bf16x8*)(m1b + (size_t)row * DIN);
        const bf16x8* ax = (const bf16x8*)(xb  + (size_t)row * DIN);
        afr[0] = am[lk];     afr[1] = am[4 + lk]; afr[2] = am[8 + lk];
        afr[3] = ax[lk];     afr[4] = ax[4 + lk]; afr[5] = ax[8 + lk];
    }

    const bf16x8* bt8 = (const bf16x8*)Bt;        // each col: 24 chunks of 8
#pragma unroll
    for (int s = 0; s < 6; ++s) {
#pragma unroll
        for (int nt = 0; nt < 8; ++nt) {
            bf16x8 bfr = bt8[(size_t)(nt * 16 + lr) * 24 + s * 4 + lk];
            acc[nt] = __builtin_amdgcn_mfma_f32_16x16x32_bf16(afr[s], bfr, acc[nt], 0, 0, 0);
        }
    }

    const int orow0 = blockIdx.x * 64 + w * 16 + lk * 4;
#pragma unroll
    for (int r = 0; r < 4; ++r) {
        const int orow = orow0 + r;
        if (orow < NN) {
#pragma unroll
            for (int nt = 0; nt < 8; ++nt)
                h[(size_t)orow * DH + nt * 16 + lr] = fmaxf(acc[nt][r], 0.f);
        }
    }
}

// ---------------- proj: zl = h @ W2l ; s = h @ W2r + b2 ----------------
#define BM2 64
__global__ __launch_bounds__(256) void k_proj(const float* __restrict__ h,
                                              const float* __restrict__ W2l,
                                              const float* __restrict__ b2,
                                              const float* __restrict__ W2r,
                                              float* __restrict__ zl,
                                              float* __restrict__ s) {
    __shared__ float sh[BM2][DH + 4];
    const int nb = blockIdx.x * BM2;
    const int tid = threadIdx.x;
#pragma unroll
    for (int it = 0; it < 8; ++it) {
        int idx = tid + it * 256;
        int m = idx >> 5, q = idx & 31;
        int row = nb + m; row = row < NN ? row : NN - 1;
        *(float4*)&sh[m][q * 4] = ((const float4*)h)[(size_t)row * (DH / 4) + q];
    }
    __syncthreads();
    const int n0 = (tid & 3) * 4;
    const int tm = tid >> 2;
    float4 al = {0.f, 0.f, 0.f, 0.f};
    float4 ar = *(const float4*)&b2[n0];
    for (int k = 0; k < DH; k += 4) {
        const float4 wl0 = *(const float4*)&W2l[(k + 0) * DOUT + n0];
        const float4 wl1 = *(const float4*)&W2l[(k + 1) * DOUT + n0];
        const float4 wl2 = *(const float4*)&W2l[(k + 2) * DOUT + n0];
        const float4 wl3 = *(const float4*)&W2l[(k + 3) * DOUT + n0];
        const float4 wr0 = *(const float4*)&W2r[(k + 0) * DOUT + n0];
        const float4 wr1 = *(const float4*)&W2r[(k + 1) * DOUT + n0];
        const float4 wr2 = *(const float4*)&W2r[(k + 2) * DOUT + n0];
        const float4 wr3 = *(const float4*)&W2r[(k + 3) * DOUT + n0];
        const float4 hv = *(const float4*)&sh[tm][k];
        al.x += hv.x * wl0.x + hv.y * wl1.x + hv.z * wl2.x + hv.w * wl3.x;
        al.y += hv.x * wl0.y + hv.y * wl1.y + hv.z * wl2.y + hv.w * wl3.y;
        al.z += hv.x * wl0.z + hv.y * wl1.z + hv.z * wl2.z + hv.w * wl3.z;
        al.w += hv.x * wl0.w + hv.y * wl1.w + hv.z * wl2.w + hv.w * wl3.w;
        ar.x += hv.x * wr0.x + hv.y * wr1.x + hv.z * wr2.x + hv.w * wr3.x;
        ar.y += hv.x * wr0.y + hv.y * wr1.y + hv.z * wr2.y + hv.w * wr3.y;
        ar.z += hv.x * wr0.z + hv.y * wr1.z + hv.z * wr2.z + hv.w * wr3.z;
        ar.w += hv.x * wr0.w + hv.y * wr1.w + hv.z * wr2.w + hv.w * wr3.w;
    }
    const int row = nb + tm;
    if (row < NN) {
        *(float4*)&zl[(size_t)row * DOUT + n0] = al;
        *(float4*)&s[(size_t)row * DOUT + n0] = ar;
    }
}

// ---------------- agg2 + softmax: out = softmax(mean(zl_nbr) + s) ----------------
__global__ __launch_bounds__(256) void k_agg2(const float* __restrict__ zl,
                                              const float* __restrict__ s,
                                              const int* __restrict__ csr,
                                              const int* __restrict__ off,
                                              float* __restrict__ out) {
    const int lane = threadIdx.x & 63;
    const int wv = threadIdx.x >> 6;
    const int g = lane >> 2;
    const int l4 = lane & 3;
    const int n = (blockIdx.x * 4 + wv) * 16 + g;
    if (n >= NN) return;
    const int b = off[n], e = off[n + 1];
    const float4* z4 = (const float4*)zl;
    float4 acc = {0.f, 0.f, 0.f, 0.f};
    int i = b;
    for (; i + 1 < e; i += 2) {
        int s0 = csr[i], s1 = csr[i + 1];
        float4 v0 = z4[(size_t)s0 * 4 + l4];
        float4 v1 = z4[(size_t)s1 * 4 + l4];
        acc.x += v0.x + v1.x; acc.y += v0.y + v1.y;
        acc.z += v0.z + v1.z; acc.w += v0.w + v1.w;
    }
    if (i < e) {
        float4 v = z4[(size_t)csr[i] * 4 + l4];
        acc.x += v.x; acc.y += v.y; acc.z += v.z; acc.w += v.w;
    }
    const float inv = (e > b) ? 1.0f / (float)(e - b) : 0.0f;
    const float4 sv = ((const float4*)s)[(size_t)n * 4 + l4];
    float4 v;
    v.x = acc.x * inv + sv.x;
    v.y = acc.y * inv + sv.y;
    v.z = acc.z * inv + sv.z;
    v.w = acc.w * inv + sv.w;
    float mx = fmaxf(fmaxf(v.x, v.y), fmaxf(v.z, v.w));
    mx = fmaxf(mx, __shfl_xor(mx, 1));
    mx = fmaxf(mx, __shfl_xor(mx, 2));
    v.x = expf(v.x - mx); v.y = expf(v.y - mx);
    v.z = expf(v.z - mx); v.w = expf(v.w - mx);
    float sm = v.x + v.y + v.z + v.w;
    sm += __shfl_xor(sm, 1);
    sm += __shfl_xor(sm, 2);
    const float r = 1.0f / sm;
    v.x *= r; v.y *= r; v.z *= r; v.w *= r;
    ((float4*)out)[(size_t)n * 4 + l4] = v;
}

template <typename T>
static inline T* align_up(void* p, size_t a = 64) {
    return (T*)(((uintptr_t)p + (a - 1)) & ~(uintptr_t)(a - 1));
}

extern "C" void kernel_launch(void* const* d_in, const int* in_sizes, int n_in,
                              void* d_out, int out_size, void* d_ws, size_t ws_size,
                              hipStream_t stream) {
    const float* x   = (const float*)d_in[0];
    const int*   ei  = (const int*)d_in[1];
    const float* W1l = (const float*)d_in[2];
    const float* b1  = (const float*)d_in[3];
    const float* W1r = (const float*)d_in[4];
    const float* W2l = (const float*)d_in[5];
    const float* b2  = (const float*)d_in[6];
    const float* W2r = (const float*)d_in[7];
    float* out = (float*)d_out;

    // workspace: floats first (16B-aligned), then ints, then bf16 arrays (64B-aligned)
    float* h  = (float*)d_ws;                                    // NN*DH
    float* zl = h + (size_t)NN * DH;                             // NN*DOUT
    float* s  = zl + (size_t)NN * DOUT;                          // NN*DOUT
    int* cnt  = (int*)(s + (size_t)NN * DOUT);                   // NN
    int* cur  = cnt + NN;                                        // NN
    int* off  = cur + NN;                                        // NN+1
    int* csr  = off + NN + 1;                                    // NE
    short* xb  = align_up<short>(csr + NE);                      // NN*DIN bf16
    short* m1b = xb + (size_t)NN * DIN;                          // NN*DIN bf16
    short* Bt  = m1b + (size_t)NN * DIN;                         // DH*192 bf16

    hipMemsetAsync(cnt, 0, (size_t)2 * NN * sizeof(int), stream);

    const int eblocks = (NE + 255) / 256;
    k_hist<<<eblocks, 256, 0, stream>>>(ei, cnt);
    k_cast_x<<<(NN * DIN / 4 + 255) / 256, 256, 0, stream>>>(x, xb);
    k_cast_w<<<(DH * 192 + 255) / 256, 256, 0, stream>>>(W1l, W1r, Bt);
    k_scan<<<1, 1024, 0, stream>>>(cnt, off);
    k_fill<<<eblocks, 256, 0, stream>>>(ei, off, cur, csr);

    k_agg1<<<(NN + 3) / 4, 256, 0, stream>>>(xb, csr, off, m1b);
    k_lin1<<<(NN + 63) / 64, 256, 0, stream>>>(m1b, xb, Bt, b1, h);
    k_proj<<<(NN + BM2 - 1) / BM2, 256, 0, stream>>>(h, W2l, b2, W2r, zl, s);
    k_agg2<<<(NN + 63) / 64, 256, 0, stream>>>(zl, s, csr, off, out);
}

// Round 6
// 198.593 us; speedup vs baseline: 2.3237x; 1.3947x over previous
//
#include <hip/hip_runtime.h>

#define NN 50000
#define NE 800000
#define DIN 96
#define DH 128
#define DOUT 16
#define SCAN_NB ((NN + 255) / 256)   // 196

typedef __attribute__((ext_vector_type(8))) short bf16x8;
typedef __attribute__((ext_vector_type(4))) float f32x4;

__device__ inline short f2bf(float f) {
    unsigned u = __float_as_uint(f);
    u += 0x7fff + ((u >> 16) & 1);          // round-to-nearest-even
    return (short)(u >> 16);
}

// ---------------- CSR build ----------------
__global__ __launch_bounds__(256) void k_hist(const int* __restrict__ ei, int* __restrict__ cnt) {
    int e = blockIdx.x * 256 + threadIdx.x;
    if (e < NE) atomicAdd(&cnt[ei[NE + e]], 1);
}

__global__ __launch_bounds__(256) void k_scan_a(const int* __restrict__ cnt, int* __restrict__ bsum) {
    int i = blockIdx.x * 256 + threadIdx.x;
    int v = (i < NN) ? cnt[i] : 0;
#pragma unroll
    for (int o = 1; o < 64; o <<= 1) v += __shfl_xor(v, o);
    __shared__ int ws4[4];
    if ((threadIdx.x & 63) == 0) ws4[threadIdx.x >> 6] = v;
    __syncthreads();
    if (threadIdx.x == 0) bsum[blockIdx.x] = ws4[0] + ws4[1] + ws4[2] + ws4[3];
}

__global__ __launch_bounds__(256) void k_scan_b(const int* __restrict__ bsum, int* __restrict__ boff) {
    __shared__ int buf[256];
    const int tid = threadIdx.x;
    int v = (tid < SCAN_NB) ? bsum[tid] : 0;
    buf[tid] = v;
    __syncthreads();
    for (int o = 1; o < 256; o <<= 1) {
        int t = (tid >= o) ? buf[tid - o] : 0;
        __syncthreads();
        buf[tid] += t;
        __syncthreads();
    }
    boff[tid] = buf[tid] - v;               // exclusive
}

__global__ __launch_bounds__(256) void k_scan_c(const int* __restrict__ cnt, const int* __restrict__ boff,
                                                int* __restrict__ off) {
    __shared__ int buf[256];
    const int tid = threadIdx.x;
    const int i = blockIdx.x * 256 + tid;
    int v = (i < NN) ? cnt[i] : 0;
    buf[tid] = v;
    __syncthreads();
    for (int o = 1; o < 256; o <<= 1) {
        int t = (tid >= o) ? buf[tid - o] : 0;
        __syncthreads();
        buf[tid] += t;
        __syncthreads();
    }
    if (i < NN) off[i] = boff[blockIdx.x] + buf[tid] - v;
    if (i == NN - 1) off[NN] = NE;
}

__global__ __launch_bounds__(256) void k_fill(const int* __restrict__ ei, const int* __restrict__ off,
                                              int* __restrict__ cur, int* __restrict__ csr) {
    int e = blockIdx.x * 256 + threadIdx.x;
    if (e < NE) {
        int d = ei[NE + e];
        int p = atomicAdd(&cur[d], 1);
        csr[off[d] + p] = ei[e];
    }
}

// ---------------- casts ----------------
__global__ __launch_bounds__(256) void k_cast_x(const float* __restrict__ x, short* __restrict__ xb) {
    int i = blockIdx.x * 256 + threadIdx.x;
    const int total = NN * DIN / 4;
    if (i >= total) return;
    float4 v = ((const float4*)x)[i];
    short4 o;
    o.x = f2bf(v.x); o.y = f2bf(v.y); o.z = f2bf(v.z); o.w = f2bf(v.w);
    ((short4*)xb)[i] = o;
}

// Bt[n][kk]: kk<96 -> W1l[kk][n], else W1r[kk-96][n]
__global__ __launch_bounds__(256) void k_cast_w(const float* __restrict__ W1l,
                                                const float* __restrict__ W1r,
                                                short* __restrict__ Bt) {
    int idx = blockIdx.x * 256 + threadIdx.x;
    if (idx >= DH * 192) return;
    int n = idx / 192, kk = idx % 192;
    float v = (kk < DIN) ? W1l[kk * DH + n] : W1r[(kk - DIN) * DH + n];
    Bt[idx] = f2bf(v);
}

// Bt2[c][k], c<16 -> W2l[k][c] ; c>=16 -> W2r[k][c-16]
__global__ __launch_bounds__(256) void k_cast_w2(const float* __restrict__ W2l,
                                                 const float* __restrict__ W2r,
                                                 short* __restrict__ Bt2) {
    int idx = blockIdx.x * 256 + threadIdx.x;
    if (idx >= 32 * DH) return;
    int c = idx >> 7, k = idx & 127;
    float v = (c < DOUT) ? W2l[k * DOUT + c] : W2r[k * DOUT + (c - DOUT)];
    Bt2[idx] = f2bf(v);
}

// ---------------- agg1: mean over neighbors of xb (bf16, 96-dim); one wave/node ----------------
__global__ __launch_bounds__(256) void k_agg1(const short* __restrict__ xb,
                                              const int* __restrict__ csr,
                                              const int* __restrict__ off,
                                              short* __restrict__ m1b) {
    const int w = threadIdx.x >> 6;
    const int l = threadIdx.x & 63;
    const int n = blockIdx.x * 4 + w;
    if (n >= NN || l >= DIN / 2) return;
    const int b = off[n], e = off[n + 1];
    const unsigned* xu = (const unsigned*)xb;
    float ax = 0.f, ay = 0.f;
    int i = b;
    for (; i + 3 < e; i += 4) {
        unsigned u0 = xu[(size_t)csr[i]     * (DIN / 2) + l];
        unsigned u1 = xu[(size_t)csr[i + 1] * (DIN / 2) + l];
        unsigned u2 = xu[(size_t)csr[i + 2] * (DIN / 2) + l];
        unsigned u3 = xu[(size_t)csr[i + 3] * (DIN / 2) + l];
        ax += __uint_as_float(u0 << 16) + __uint_as_float(u1 << 16)
            + __uint_as_float(u2 << 16) + __uint_as_float(u3 << 16);
        ay += __uint_as_float(u0 & 0xffff0000u) + __uint_as_float(u1 & 0xffff0000u)
            + __uint_as_float(u2 & 0xffff0000u) + __uint_as_float(u3 & 0xffff0000u);
    }
    for (; i < e; ++i) {
        unsigned u = xu[(size_t)csr[i] * (DIN / 2) + l];
        ax += __uint_as_float(u << 16);
        ay += __uint_as_float(u & 0xffff0000u);
    }
    const float inv = (e > b) ? 1.0f / (float)(e - b) : 0.0f;
    ax *= inv; ay *= inv;
    unsigned o = (unsigned)(unsigned short)f2bf(ax) | ((unsigned)(unsigned short)f2bf(ay) << 16);
    ((unsigned*)m1b)[(size_t)n * (DIN / 2) + l] = o;
}

// ---------------- lin1 MFMA: hb = relu([m1b, xb] @ Bt^T + b1) in bf16 ----------------
__global__ __launch_bounds__(256) void k_lin1(const short* __restrict__ m1b,
                                              const short* __restrict__ xb,
                                              const short* __restrict__ Bt,
                                              const float* __restrict__ b1,
                                              short* __restrict__ hb) {
    const int w = threadIdx.x >> 6;
    const int l = threadIdx.x & 63;
    const int lr = l & 15;
    const int lk = l >> 4;
    int row = blockIdx.x * 64 + w * 16 + lr;
    if (row >= NN) row = NN - 1;

    f32x4 acc[8];
#pragma unroll
    for (int nt = 0; nt < 8; ++nt) {
        float bv = b1[nt * 16 + lr];
        acc[nt] = (f32x4){bv, bv, bv, bv};
    }

    bf16x8 afr[6];
    {
        const bf16x8* am = (const bf16x8*)(m1b + (size_t)row * DIN);
        const bf16x8* ax = (const bf16x8*)(xb  + (size_t)row * DIN);
        afr[0] = am[lk];     afr[1] = am[4 + lk]; afr[2] = am[8 + lk];
        afr[3] = ax[lk];     afr[4] = ax[4 + lk]; afr[5] = ax[8 + lk];
    }

    const bf16x8* bt8 = (const bf16x8*)Bt;
#pragma unroll
    for (int s = 0; s < 6; ++s) {
#pragma unroll
        for (int nt = 0; nt < 8; ++nt) {
            bf16x8 bfr = bt8[(size_t)(nt * 16 + lr) * 24 + s * 4 + lk];
            acc[nt] = __builtin_amdgcn_mfma_f32_16x16x32_bf16(afr[s], bfr, acc[nt], 0, 0, 0);
        }
    }

    const int orow0 = blockIdx.x * 64 + w * 16 + lk * 4;
#pragma unroll
    for (int r = 0; r < 4; ++r) {
        const int orow = orow0 + r;
        if (orow < NN) {
#pragma unroll
            for (int nt = 0; nt < 8; ++nt)
                hb[(size_t)orow * DH + nt * 16 + lr] = f2bf(fmaxf(acc[nt][r], 0.f));
        }
    }
}

// ---------------- proj MFMA: zlb = hb @ W2l (bf16) ; s = hb @ W2r + b2 (f32) ----------------
__global__ __launch_bounds__(256) void k_proj(const short* __restrict__ hb,
                                              const short* __restrict__ Bt2,
                                              const float* __restrict__ b2,
                                              short* __restrict__ zlb,
                                              float* __restrict__ s) {
    const int w = threadIdx.x >> 6;
    const int l = threadIdx.x & 63;
    const int lr = l & 15;
    const int lk = l >> 4;
    int row = blockIdx.x * 64 + w * 16 + lr;
    if (row >= NN) row = NN - 1;

    bf16x8 afr[4];
    {
        const bf16x8* a8 = (const bf16x8*)(hb + (size_t)row * DH);
        afr[0] = a8[lk]; afr[1] = a8[4 + lk]; afr[2] = a8[8 + lk]; afr[3] = a8[12 + lk];
    }

    f32x4 accz = (f32x4){0.f, 0.f, 0.f, 0.f};
    float bv = b2[lr];
    f32x4 accs = (f32x4){bv, bv, bv, bv};
    const bf16x8* b8 = (const bf16x8*)Bt2;        // [32 cols][16 chunks]
#pragma unroll
    for (int st = 0; st < 4; ++st) {
        bf16x8 bz = b8[(size_t)lr * 16 + st * 4 + lk];
        bf16x8 bs = b8[(size_t)(16 + lr) * 16 + st * 4 + lk];
        accz = __builtin_amdgcn_mfma_f32_16x16x32_bf16(afr[st], bz, accz, 0, 0, 0);
        accs = __builtin_amdgcn_mfma_f32_16x16x32_bf16(afr[st], bs, accs, 0, 0, 0);
    }

    const int orow0 = blockIdx.x * 64 + w * 16 + lk * 4;
#pragma unroll
    for (int r = 0; r < 4; ++r) {
        const int orow = orow0 + r;
        if (orow < NN) {
            zlb[(size_t)orow * DOUT + lr] = f2bf(accz[r]);
            s[(size_t)orow * DOUT + lr] = accs[r];
        }
    }
}

// ---------------- agg2 + softmax: out = softmax(mean(zlb_nbr) + s) ----------------
// one wave per node; 16 neighbors in flight (quad per neighbor row)
__global__ __launch_bounds__(256) void k_agg2(const short* __restrict__ zlb,
                                              const float* __restrict__ s,
                                              const int* __restrict__ csr,
                                              const int* __restrict__ off,
                                              float* __restrict__ out) {
    const int w = threadIdx.x >> 6;
    const int lane = threadIdx.x & 63;
    const int n = blockIdx.x * 4 + w;
    if (n >= NN) return;
    const int b = off[n], e = off[n + 1];
    const int ng = lane >> 2;          // neighbor slot 0..15
    const int sl = lane & 3;           // quarter of the 16-wide row
    const uint2* z2 = (const uint2*)zlb;   // row = 4 x uint2
    float4 acc = {0.f, 0.f, 0.f, 0.f};
    for (int i = b + ng; i < e; i += 16) {
        uint2 u = z2[(size_t)csr[i] * 4 + sl];
        acc.x += __uint_as_float(u.x << 16);
        acc.y += __uint_as_float(u.x & 0xffff0000u);
        acc.z += __uint_as_float(u.y << 16);
        acc.w += __uint_as_float(u.y & 0xffff0000u);
    }
#pragma unroll
    for (int o = 4; o <= 32; o <<= 1) {
        acc.x += __shfl_xor(acc.x, o);
        acc.y += __shfl_xor(acc.y, o);
        acc.z += __shfl_xor(acc.z, o);
        acc.w += __shfl_xor(acc.w, o);
    }
    const float inv = (e > b) ? 1.0f / (float)(e - b) : 0.0f;
    const float4 sv = ((const float4*)s)[(size_t)n * 4 + sl];
    float4 v;
    v.x = acc.x * inv + sv.x;
    v.y = acc.y * inv + sv.y;
    v.z = acc.z * inv + sv.z;
    v.w = acc.w * inv + sv.w;
    float mx = fmaxf(fmaxf(v.x, v.y), fmaxf(v.z, v.w));
    mx = fmaxf(mx, __shfl_xor(mx, 1));
    mx = fmaxf(mx, __shfl_xor(mx, 2));
    v.x = expf(v.x - mx); v.y = expf(v.y - mx);
    v.z = expf(v.z - mx); v.w = expf(v.w - mx);
    float sm = v.x + v.y + v.z + v.w;
    sm += __shfl_xor(sm, 1);
    sm += __shfl_xor(sm, 2);
    const float r = 1.0f / sm;
    v.x *= r; v.y *= r; v.z *= r; v.w *= r;
    if (ng == 0) ((float4*)out)[(size_t)n * 4 + sl] = v;
}

template <typename T>
static inline T* align_up(void* p, size_t a = 64) {
    return (T*)(((uintptr_t)p + (a - 1)) & ~(uintptr_t)(a - 1));
}

extern "C" void kernel_launch(void* const* d_in, const int* in_sizes, int n_in,
                              void* d_out, int out_size, void* d_ws, size_t ws_size,
                              hipStream_t stream) {
    const float* x   = (const float*)d_in[0];
    const int*   ei  = (const int*)d_in[1];
    const float* W1l = (const float*)d_in[2];
    const float* b1  = (const float*)d_in[3];
    const float* W1r = (const float*)d_in[4];
    const float* W2l = (const float*)d_in[5];
    const float* b2  = (const float*)d_in[6];
    const float* W2r = (const float*)d_in[7];
    float* out = (float*)d_out;

    // workspace: f32, then ints, then bf16 (64B aligned)
    float* s  = (float*)d_ws;                                    // NN*DOUT
    int* cnt  = (int*)(s + (size_t)NN * DOUT);                   // NN
    int* cur  = cnt + NN;                                        // NN
    int* off  = cur + NN;                                        // NN+1
    int* bsum = off + NN + 1;                                    // 256
    int* boff = bsum + 256;                                      // 256
    int* csr  = boff + 256;                                      // NE
    short* xb  = align_up<short>(csr + NE);                      // NN*DIN
    short* m1b = xb + (size_t)NN * DIN;                          // NN*DIN
    short* hb  = m1b + (size_t)NN * DIN;                         // NN*DH
    short* zlb = hb + (size_t)NN * DH;                           // NN*DOUT
    short* Bt  = zlb + (size_t)NN * DOUT;                        // DH*192
    short* Bt2 = Bt + (size_t)DH * 192;                          // 32*DH

    hipMemsetAsync(cnt, 0, (size_t)2 * NN * sizeof(int), stream);

    const int eblocks = (NE + 255) / 256;
    k_hist<<<eblocks, 256, 0, stream>>>(ei, cnt);
    k_cast_x<<<(NN * DIN / 4 + 255) / 256, 256, 0, stream>>>(x, xb);
    k_cast_w<<<(DH * 192 + 255) / 256, 256, 0, stream>>>(W1l, W1r, Bt);
    k_cast_w2<<<(32 * DH + 255) / 256, 256, 0, stream>>>(W2l, W2r, Bt2);
    k_scan_a<<<SCAN_NB, 256, 0, stream>>>(cnt, bsum);
    k_scan_b<<<1, 256, 0, stream>>>(bsum, boff);
    k_scan_c<<<SCAN_NB, 256, 0, stream>>>(cnt, boff, off);
    k_fill<<<eblocks, 256, 0, stream>>>(ei, off, cur, csr);

    k_agg1<<<(NN + 3) / 4, 256, 0, stream>>>(xb, csr, off, m1b);
    k_lin1<<<(NN + 63) / 64, 256, 0, stream>>>(m1b, xb, Bt, b1, hb);
    k_proj<<<(NN + 63) / 64, 256, 0, stream>>>(hb, Bt2, b2, zlb, s);
    k_agg2<<<(NN + 3) / 4, 256, 0, stream>>>(zlb, s, csr, off, out);
}

// Round 7
// 149.320 us; speedup vs baseline: 3.0905x; 1.3300x over previous
//
#include <hip/hip_runtime.h>

#define NN 50000
#define NE 800000
#define DIN 96
#define DH 128
#define DOUT 16
#define NBKT ((NN + 127) / 128)     // 391 buckets of 128 nodes
#define EPB 4096                     // edges per phase-A block

typedef __attribute__((ext_vector_type(8))) short bf16x8;
typedef __attribute__((ext_vector_type(4))) float f32x4;

__device__ inline short f2bf(float f) {
    unsigned u = __float_as_uint(f);
    u += 0x7fff + ((u >> 16) & 1);          // round-to-nearest-even
    return (short)(u >> 16);
}

// ---------------- bucket histogram (LDS-staged) ----------------
__global__ __launch_bounds__(256) void k_bhist(const int* __restrict__ ei, int* __restrict__ bcntg) {
    __shared__ int h[NBKT];
    for (int i = threadIdx.x; i < NBKT; i += 256) h[i] = 0;
    __syncthreads();
    const int base = blockIdx.x * 8192;
    const int end = min(base + 8192, NE);
    for (int i = base + threadIdx.x; i < end; i += 256)
        atomicAdd(&h[ei[NE + i] >> 7], 1);
    __syncthreads();
    for (int b = threadIdx.x; b < NBKT; b += 256)
        if (h[b]) atomicAdd(&bcntg[b], h[b]);
}

// ---------------- bucket scan: boff (exclusive), gbcur = boff ----------------
__global__ __launch_bounds__(512) void k_bscan(const int* __restrict__ bcntg,
                                               int* __restrict__ boff, int* __restrict__ gbcur) {
    __shared__ int buf[512];
    const int t = threadIdx.x;
    int v = (t < NBKT) ? bcntg[t] : 0;
    buf[t] = v;
    __syncthreads();
    for (int o = 1; o < 512; o <<= 1) {
        int tv = (t >= o) ? buf[t - o] : 0;
        __syncthreads();
        buf[t] += tv;
        __syncthreads();
    }
    if (t < NBKT) {
        int ex = buf[t] - v;
        boff[t] = ex;
        gbcur[t] = ex;
    }
    if (t == 0) boff[NBKT] = NE;
}

// ---------------- phase A: LDS-staged bucket scatter of (src,dst) pairs ----------------
__global__ __launch_bounds__(512) void k_bucket(const int* __restrict__ ei,
                                                int* __restrict__ gbcur,
                                                uint2* __restrict__ bpair) {
    __shared__ uint2 stage[EPB];        // 32 KB
    __shared__ int bcnt[NBKT];
    __shared__ int bfill[NBKT];
    __shared__ int brun[NBKT];
    __shared__ int bres[NBKT];
    __shared__ int sbuf[512];
    const int tid = threadIdx.x;
    const int e0 = blockIdx.x * EPB;
    const int ecnt = min(EPB, NE - e0);

    for (int i = tid; i < NBKT; i += 512) { bcnt[i] = 0; bfill[i] = 0; }
    __syncthreads();
    for (int i = tid; i < ecnt; i += 512)
        atomicAdd(&bcnt[(unsigned)ei[NE + e0 + i] >> 7], 1);
    __syncthreads();
    // exclusive scan of bcnt -> brun
    int v = (tid < NBKT) ? bcnt[tid] : 0;
    sbuf[tid] = v;
    __syncthreads();
    for (int o = 1; o < 512; o <<= 1) {
        int tv = (tid >= o) ? sbuf[tid - o] : 0;
        __syncthreads();
        sbuf[tid] += tv;
        __syncthreads();
    }
    if (tid < NBKT) brun[tid] = sbuf[tid] - v;
    __syncthreads();
    // slot pairs into stage grouped by bucket
    for (int i = tid; i < ecnt; i += 512) {
        unsigned s = (unsigned)ei[e0 + i];
        unsigned d = (unsigned)ei[NE + e0 + i];
        int b = d >> 7;
        int p = atomicAdd(&bfill[b], 1);
        stage[brun[b] + p] = make_uint2(s, d);
    }
    __syncthreads();
    // reserve global space per bucket
    for (int b = tid; b < NBKT; b += 512) {
        int n = bcnt[b];
        bres[b] = n ? atomicAdd(&gbcur[b], n) : 0;
    }
    __syncthreads();
    // flush contiguous runs
    for (int i = tid; i < ecnt; i += 512) {
        uint2 pr = stage[i];
        int b = pr.y >> 7;
        bpair[bres[b] + (i - brun[b])] = pr;
    }
}

// ---------------- phase B1: per-bucket node histogram + scan -> off ----------------
__global__ __launch_bounds__(128) void k_b1(const uint2* __restrict__ bpair,
                                            const int* __restrict__ boff,
                                            int* __restrict__ off) {
    __shared__ int ncnt[128];
    __shared__ int buf[128];
    const int b = blockIdx.x;
    const int tid = threadIdx.x;
    ncnt[tid] = 0;
    __syncthreads();
    const int pb = boff[b], pe = boff[b + 1];
    for (int i = pb + tid; i < pe; i += 128)
        atomicAdd(&ncnt[bpair[i].y & 127], 1);
    __syncthreads();
    int v = ncnt[tid];
    buf[tid] = v;
    __syncthreads();
    for (int o = 1; o < 128; o <<= 1) {
        int tv = (tid >= o) ? buf[tid - o] : 0;
        __syncthreads();
        buf[tid] += tv;
        __syncthreads();
    }
    const int n = b * 128 + tid;
    if (n <= NN) off[n] = pb + buf[tid] - v;   // exclusive; n==NN lands on NE
}

// ---------------- phase B2: per-bucket rank + fill csr ----------------
__global__ __launch_bounds__(256) void k_b2(const uint2* __restrict__ bpair,
                                            const int* __restrict__ boff,
                                            const int* __restrict__ off,
                                            int* __restrict__ csr) {
    __shared__ int lcur[128];
    const int b = blockIdx.x;
    const int tid = threadIdx.x;
    if (tid < 128) lcur[tid] = 0;
    __syncthreads();
    const int pb = boff[b], pe = boff[b + 1];
    for (int i = pb + tid; i < pe; i += 256) {
        uint2 pr = bpair[i];
        int p = atomicAdd(&lcur[pr.y & 127], 1);
        csr[off[pr.y] + p] = (int)pr.x;
    }
}

// ---------------- casts ----------------
__global__ __launch_bounds__(256) void k_cast_x(const float* __restrict__ x, short* __restrict__ xb) {
    int i = blockIdx.x * 256 + threadIdx.x;
    const int total = NN * DIN / 4;
    if (i >= total) return;
    float4 v = ((const float4*)x)[i];
    short4 o;
    o.x = f2bf(v.x); o.y = f2bf(v.y); o.z = f2bf(v.z); o.w = f2bf(v.w);
    ((short4*)xb)[i] = o;
}

// fused: Bt[n][kk] (layer1) then Bt2[c][k] (layer2)
__global__ __launch_bounds__(256) void k_cast_w(const float* __restrict__ W1l,
                                                const float* __restrict__ W1r,
                                                const float* __restrict__ W2l,
                                                const float* __restrict__ W2r,
                                                short* __restrict__ Bt,
                                                short* __restrict__ Bt2) {
    int idx = blockIdx.x * 256 + threadIdx.x;
    if (idx < DH * 192) {
        int n = idx / 192, kk = idx % 192;
        float v = (kk < DIN) ? W1l[kk * DH + n] : W1r[(kk - DIN) * DH + n];
        Bt[idx] = f2bf(v);
    } else if (idx < DH * 192 + 32 * DH) {
        int j = idx - DH * 192;
        int c = j >> 7, k = j & 127;
        float v = (c < DOUT) ? W2l[k * DOUT + c] : W2r[k * DOUT + (c - DOUT)];
        Bt2[j] = f2bf(v);
    }
}

// ---------------- agg1: mean over neighbors of xb (bf16, 96-dim); one wave/node ----------------
__global__ __launch_bounds__(256) void k_agg1(const short* __restrict__ xb,
                                              const int* __restrict__ csr,
                                              const int* __restrict__ off,
                                              short* __restrict__ m1b) {
    const int w = threadIdx.x >> 6;
    const int l = threadIdx.x & 63;
    const int n = blockIdx.x * 4 + w;
    if (n >= NN || l >= DIN / 2) return;
    const int b = off[n], e = off[n + 1];
    const unsigned* xu = (const unsigned*)xb;
    float ax = 0.f, ay = 0.f;
    int i = b;
    for (; i + 3 < e; i += 4) {
        unsigned u0 = xu[(size_t)csr[i]     * (DIN / 2) + l];
        unsigned u1 = xu[(size_t)csr[i + 1] * (DIN / 2) + l];
        unsigned u2 = xu[(size_t)csr[i + 2] * (DIN / 2) + l];
        unsigned u3 = xu[(size_t)csr[i + 3] * (DIN / 2) + l];
        ax += __uint_as_float(u0 << 16) + __uint_as_float(u1 << 16)
            + __uint_as_float(u2 << 16) + __uint_as_float(u3 << 16);
        ay += __uint_as_float(u0 & 0xffff0000u) + __uint_as_float(u1 & 0xffff0000u)
            + __uint_as_float(u2 & 0xffff0000u) + __uint_as_float(u3 & 0xffff0000u);
    }
    for (; i < e; ++i) {
        unsigned u = xu[(size_t)csr[i] * (DIN / 2) + l];
        ax += __uint_as_float(u << 16);
        ay += __uint_as_float(u & 0xffff0000u);
    }
    const float inv = (e > b) ? 1.0f / (float)(e - b) : 0.0f;
    ax *= inv; ay *= inv;
    unsigned o = (unsigned)(unsigned short)f2bf(ax) | ((unsigned)(unsigned short)f2bf(ay) << 16);
    ((unsigned*)m1b)[(size_t)n * (DIN / 2) + l] = o;
}

// ---------------- lin1 MFMA: hb = relu([m1b, xb] @ Bt^T + b1) in bf16 ----------------
__global__ __launch_bounds__(256) void k_lin1(const short* __restrict__ m1b,
                                              const short* __restrict__ xb,
                                              const short* __restrict__ Bt,
                                              const float* __restrict__ b1,
                                              short* __restrict__ hb) {
    const int w = threadIdx.x >> 6;
    const int l = threadIdx.x & 63;
    const int lr = l & 15;
    const int lk = l >> 4;
    int row = blockIdx.x * 64 + w * 16 + lr;
    if (row >= NN) row = NN - 1;

    f32x4 acc[8];
#pragma unroll
    for (int nt = 0; nt < 8; ++nt) {
        float bv = b1[nt * 16 + lr];
        acc[nt] = (f32x4){bv, bv, bv, bv};
    }

    bf16x8 afr[6];
    {
        const bf16x8* am = (const bf16x8*)(m1b + (size_t)row * DIN);
        const bf16x8* ax = (const bf16x8*)(xb  + (size_t)row * DIN);
        afr[0] = am[lk];     afr[1] = am[4 + lk]; afr[2] = am[8 + lk];
        afr[3] = ax[lk];     afr[4] = ax[4 + lk]; afr[5] = ax[8 + lk];
    }

    const bf16x8* bt8 = (const bf16x8*)Bt;
#pragma unroll
    for (int s = 0; s < 6; ++s) {
#pragma unroll
        for (int nt = 0; nt < 8; ++nt) {
            bf16x8 bfr = bt8[(size_t)(nt * 16 + lr) * 24 + s * 4 + lk];
            acc[nt] = __builtin_amdgcn_mfma_f32_16x16x32_bf16(afr[s], bfr, acc[nt], 0, 0, 0);
        }
    }

    const int orow0 = blockIdx.x * 64 + w * 16 + lk * 4;
#pragma unroll
    for (int r = 0; r < 4; ++r) {
        const int orow = orow0 + r;
        if (orow < NN) {
#pragma unroll
            for (int nt = 0; nt < 8; ++nt)
                hb[(size_t)orow * DH + nt * 16 + lr] = f2bf(fmaxf(acc[nt][r], 0.f));
        }
    }
}

// ---------------- proj MFMA: zlb = hb @ W2l (bf16) ; s = hb @ W2r + b2 (f32) ----------------
__global__ __launch_bounds__(256) void k_proj(const short* __restrict__ hb,
                                              const short* __restrict__ Bt2,
                                              const float* __restrict__ b2,
                                              short* __restrict__ zlb,
                                              float* __restrict__ s) {
    const int w = threadIdx.x >> 6;
    const int l = threadIdx.x & 63;
    const int lr = l & 15;
    const int lk = l >> 4;
    int row = blockIdx.x * 64 + w * 16 + lr;
    if (row >= NN) row = NN - 1;

    bf16x8 afr[4];
    {
        const bf16x8* a8 = (const bf16x8*)(hb + (size_t)row * DH);
        afr[0] = a8[lk]; afr[1] = a8[4 + lk]; afr[2] = a8[8 + lk]; afr[3] = a8[12 + lk];
    }

    f32x4 accz = (f32x4){0.f, 0.f, 0.f, 0.f};
    float bv = b2[lr];
    f32x4 accs = (f32x4){bv, bv, bv, bv};
    const bf16x8* b8 = (const bf16x8*)Bt2;        // [32 cols][16 chunks]
#pragma unroll
    for (int st = 0; st < 4; ++st) {
        bf16x8 bz = b8[(size_t)lr * 16 + st * 4 + lk];
        bf16x8 bs = b8[(size_t)(16 + lr) * 16 + st * 4 + lk];
        accz = __builtin_amdgcn_mfma_f32_16x16x32_bf16(afr[st], bz, accz, 0, 0, 0);
        accs = __builtin_amdgcn_mfma_f32_16x16x32_bf16(afr[st], bs, accs, 0, 0, 0);
    }

    const int orow0 = blockIdx.x * 64 + w * 16 + lk * 4;
#pragma unroll
    for (int r = 0; r < 4; ++r) {
        const int orow = orow0 + r;
        if (orow < NN) {
            zlb[(size_t)orow * DOUT + lr] = f2bf(accz[r]);
            s[(size_t)orow * DOUT + lr] = accs[r];
        }
    }
}

// ---------------- agg2 + softmax: out = softmax(mean(zlb_nbr) + s) ----------------
__global__ __launch_bounds__(256) void k_agg2(const short* __restrict__ zlb,
                                              const float* __restrict__ s,
                                              const int* __restrict__ csr,
                                              const int* __restrict__ off,
                                              float* __restrict__ out) {
    const int w = threadIdx.x >> 6;
    const int lane = threadIdx.x & 63;
    const int n = blockIdx.x * 4 + w;
    if (n >= NN) return;
    const int b = off[n], e = off[n + 1];
    const int ng = lane >> 2;
    const int sl = lane & 3;
    const uint2* z2 = (const uint2*)zlb;
    float4 acc = {0.f, 0.f, 0.f, 0.f};
    for (int i = b + ng; i < e; i += 16) {
        uint2 u = z2[(size_t)csr[i] * 4 + sl];
        acc.x += __uint_as_float(u.x << 16);
        acc.y += __uint_as_float(u.x & 0xffff0000u);
        acc.z += __uint_as_float(u.y << 16);
        acc.w += __uint_as_float(u.y & 0xffff0000u);
    }
#pragma unroll
    for (int o = 4; o <= 32; o <<= 1) {
        acc.x += __shfl_xor(acc.x, o);
        acc.y += __shfl_xor(acc.y, o);
        acc.z += __shfl_xor(acc.z, o);
        acc.w += __shfl_xor(acc.w, o);
    }
    const float inv = (e > b) ? 1.0f / (float)(e - b) : 0.0f;
    const float4 sv = ((const float4*)s)[(size_t)n * 4 + sl];
    float4 v;
    v.x = acc.x * inv + sv.x;
    v.y = acc.y * inv + sv.y;
    v.z = acc.z * inv + sv.z;
    v.w = acc.w * inv + sv.w;
    float mx = fmaxf(fmaxf(v.x, v.y), fmaxf(v.z, v.w));
    mx = fmaxf(mx, __shfl_xor(mx, 1));
    mx = fmaxf(mx, __shfl_xor(mx, 2));
    v.x = expf(v.x - mx); v.y = expf(v.y - mx);
    v.z = expf(v.z - mx); v.w = expf(v.w - mx);
    float sm = v.x + v.y + v.z + v.w;
    sm += __shfl_xor(sm, 1);
    sm += __shfl_xor(sm, 2);
    const float r = 1.0f / sm;
    v.x *= r; v.y *= r; v.z *= r; v.w *= r;
    if (ng == 0) ((float4*)out)[(size_t)n * 4 + sl] = v;
}

template <typename T>
static inline T* align_up(void* p, size_t a = 64) {
    return (T*)(((uintptr_t)p + (a - 1)) & ~(uintptr_t)(a - 1));
}

extern "C" void kernel_launch(void* const* d_in, const int* in_sizes, int n_in,
                              void* d_out, int out_size, void* d_ws, size_t ws_size,
                              hipStream_t stream) {
    const float* x   = (const float*)d_in[0];
    const int*   ei  = (const int*)d_in[1];
    const float* W1l = (const float*)d_in[2];
    const float* b1  = (const float*)d_in[3];
    const float* W1r = (const float*)d_in[4];
    const float* W2l = (const float*)d_in[5];
    const float* b2  = (const float*)d_in[6];
    const float* W2r = (const float*)d_in[7];
    float* out = (float*)d_out;

    // workspace layout
    uint2* bpair = (uint2*)d_ws;                                 // NE (8B aligned)
    float* s     = (float*)(bpair + NE);                         // NN*DOUT
    int* off     = (int*)(s + (size_t)NN * DOUT);                // NN+1
    int* boff    = off + NN + 1;                                 // NBKT+1
    int* gbcur   = boff + NBKT + 1;                              // NBKT
    int* bcntg   = gbcur + NBKT;                                 // NBKT
    int* csr     = bcntg + NBKT;                                 // NE
    short* xb    = align_up<short>(csr + NE);                    // NN*DIN
    short* m1b   = xb + (size_t)NN * DIN;                        // NN*DIN
    short* hb    = m1b + (size_t)NN * DIN;                       // NN*DH
    short* zlb   = hb + (size_t)NN * DH;                         // NN*DOUT
    short* Bt    = zlb + (size_t)NN * DOUT;                      // DH*192
    short* Bt2   = Bt + (size_t)DH * 192;                        // 32*DH

    hipMemsetAsync(bcntg, 0, NBKT * sizeof(int), stream);

    k_bhist<<<(NE + 8191) / 8192, 256, 0, stream>>>(ei, bcntg);
    k_cast_x<<<(NN * DIN / 4 + 255) / 256, 256, 0, stream>>>(x, xb);
    k_cast_w<<<(DH * 192 + 32 * DH + 255) / 256, 256, 0, stream>>>(W1l, W1r, W2l, W2r, Bt, Bt2);
    k_bscan<<<1, 512, 0, stream>>>(bcntg, boff, gbcur);
    k_bucket<<<(NE + EPB - 1) / EPB, 512, 0, stream>>>(ei, gbcur, bpair);
    k_b1<<<NBKT, 128, 0, stream>>>(bpair, boff, off);
    k_b2<<<NBKT, 256, 0, stream>>>(bpair, boff, off, csr);

    k_agg1<<<(NN + 3) / 4, 256, 0, stream>>>(xb, csr, off, m1b);
    k_lin1<<<(NN + 63) / 64, 256, 0, stream>>>(m1b, xb, Bt, b1, hb);
    k_proj<<<(NN + 63) / 64, 256, 0, stream>>>(hb, Bt2, b2, zlb, s);
    k_agg2<<<(NN + 3) / 4, 256, 0, stream>>>(zlb, s, csr, off, out);
}